// Round 15
// baseline (207.544 us; speedup 1.0000x reference)
//
#include <hip/hip_runtime.h>
#include <hip/hip_cooperative_groups.h>

namespace cg = cooperative_groups;

// NEUROPULS unitary mesh, N=256 — R18: R17's verified 3-phase decomposition
// in ONE cooperative launch.
// R17 post-mortem: kernel work only ~22us (coef 3 + 64-stage group 15 +
// combine 4) but dur implied ~41us — each extra dependent dispatch costs
// ~5-9us in this harness (consistent across R13/R14/R17). The chain-halving
// works (group = 64 x 226ns, same rate as monolithic); launch gaps erased
// it. Fix: one cooperative kernel, cg::grid.sync() between phases (guide
// §1: sanctioned; 512 blocks x 64 thr = 2 blocks/CU, 96KB LDS/CU resident).
//   Phase 0: blocks 0..127 -> per-stage coefs        (R17 body, verified)
//   Phase A: 512 blocks -> two 64-stage half-operators (R17, verified)
//   Phase B: 512 blocks -> zero-LDS combine M = P2 x P1 (R17 math, 64-lane
//            remap: block j -> row j>>1, col half j&1, 2 dots/lane)
// ws (floats): coefs[98304] | P1 @98304 (float2 row-major) | P2 @229376.

__device__ __forceinline__ float dpp_up1(float x) {   // wave_shr:1, n <- n-1
    return __int_as_float(__builtin_amdgcn_update_dpp(
        __float_as_int(x), __float_as_int(x), 0x138, 0xf, 0xf, false));
}
__device__ __forceinline__ float dpp_dn1(float x) {   // wave_shl:1, n <- n+1
    return __int_as_float(__builtin_amdgcn_update_dpp(
        __float_as_int(x), __float_as_int(x), 0x130, 0xf, 0xf, false));
}
__device__ __forceinline__ void sincos4(float4 th, float sn[4], float cs[4]) {
    __sincosf(th.x, &sn[0], &cs[0]);
    __sincosf(th.y, &sn[1], &cs[1]);
    __sincosf(th.z, &sn[2], &cs[2]);
    __sincosf(th.w, &sn[3], &cs[3]);
}

// packed complex helpers (verified R16/R17)
__device__ __forceinline__ float2 cmul_pk(float2 K, float2 z) {
    float2 t;
    asm("v_pk_mul_f32 %0, %1, %2 op_sel:[0,0] op_sel_hi:[0,1]\n\t"
        "v_pk_fma_f32 %0, %1, %2, %0 op_sel:[1,1,0] op_sel_hi:[1,0,1] neg_lo:[1,0,0]"
        : "=&v"(t) : "v"(K), "v"(z));
    return t;
}
__device__ __forceinline__ float2 cfma_pk(float2 K, float2 z, float2 acc) {
    asm("v_pk_fma_f32 %0, %1, %2, %0 op_sel:[0,0,0] op_sel_hi:[0,1,1]\n\t"
        "v_pk_fma_f32 %0, %1, %2, %0 op_sel:[1,1,0] op_sel_hi:[1,0,1] neg_lo:[1,0,0]"
        : "+v"(acc) : "v"(K), "v"(z));
    return acc;
}
__device__ __forceinline__ float2 cross_pk(float2 K, float2 z, float2 p) {
    float2 t;
    asm("v_pk_mul_f32 %0, %1, %2 op_sel:[0,0] op_sel_hi:[0,1]\n\t"
        "v_pk_fma_f32 %0, %1, %3, %0 op_sel:[1,1,0] op_sel_hi:[1,0,1] neg_lo:[1,0,0]"
        : "=&v"(t) : "v"(K), "v"(z), "v"(p));
    return t;
}

__global__ __launch_bounds__(64, 1)
void fused_kernel(const float* __restrict__ thetas,  // [130,256]
                  float* __restrict__ ws,
                  float* __restrict__ out)           // re[65536] || im[65536]
{
    constexpr int N = 256;
    __shared__ float4 cbuf[2][1536];   // 2 x 24 KB (phase A only)

    cg::grid_group grid = cg::this_grid();

    const int j    = blockIdx.x;    // 0..511
    const int lane = threadIdx.x;   // 0..63

    const float U  = 0.98f * 0.505f;                  // AT^2
    const float W  = 0.98f * 0.495f;                  // AR^2
    const float Gc = 0.98f * sqrtf(0.505f * 0.495f);  // AT*AR
    const float BT = sqrtf(0.98f * 0.01f);            // CR a*sqrt(CT)
    const float BR = sqrtf(0.98f * 0.99f);            // CR thru amplitude

    // ================= phase 0: per-stage collapsed coefficients ==========
    if (j < 128) {
        float4 th = *(const float4*)(thetas + (j + 1) * 256 + 4 * lane);
        float s[4], c[4];
        sincos4(th, s, c);
        float4 A, B, C;
        A.x = U * c[0] - W * c[1];   A.y = U * s[0] - W * s[1];   // E0
        A.z = U * c[1] - W * c[0];   A.w = U * s[1] - W * s[0];   // F0
        B.x = -Gc * (s[0] + s[1]);   B.y = Gc * (c[0] + c[1]);    // G0
        B.z = -Gc * (s[2] + s[3]);   B.w = Gc * (c[2] + c[3]);    // G1
        C.x = U * c[2] - W * c[3];   C.y = U * s[2] - W * s[3];   // E1
        C.z = U * c[3] - W * c[2];   C.w = U * s[3] - W * s[2];   // F1
        float4* cp = (float4*)ws;
        cp[(j * 3 + 0) * 64 + lane] = A;
        cp[(j * 3 + 1) * 64 + lane] = B;
        cp[(j * 3 + 2) * 64 + lane] = C;
    }
    grid.sync();

    // ================= phase A: 64-stage half-operators ====================
    {
        const int g    = j >> 8;         // 0: stages 1..64; 1: 65..128
        const int col  = j & 255;
        const int base = g * 8;          // global chunk offset
        const float* coefs = ws;

        const float2 CK  = make_float2(BT, BR);
        const float2 EC0 = (lane == 0)  ? make_float2(BR, 0.f) : CK;
        const float2 EC3 = (lane == 63) ? make_float2(BR, 0.f) : CK;

        float2 z0 = make_float2(0.f, 0.f), z1 = z0, z2 = z0, z3 = z0;
        {
            const int r0 = col - 4 * lane;
            if (0 <= r0 && r0 < 4) {
                float2 v = make_float2(1.f, 0.f);
                if (g == 0) {
                    float s0, c0;
                    __sincosf(thetas[col], &s0, &c0);
                    v = make_float2(c0, s0);
                }
                if (r0 == 0) z0 = v; else if (r0 == 1) z1 = v;
                else if (r0 == 2) z2 = v; else z3 = v;
            }
        }

        auto mstep = [&](const float4& KA, const float4& KB, const float4& KC) {
            const float2 E0 = make_float2(KA.x, KA.y), F0 = make_float2(KA.z, KA.w);
            const float2 G0 = make_float2(KB.x, KB.y), G1 = make_float2(KB.z, KB.w);
            const float2 E1 = make_float2(KC.x, KC.y), F1 = make_float2(KC.z, KC.w);
            const float2 nx0 = cfma_pk(G0, z1, cmul_pk(E0, z0));
            const float2 ny0 = cfma_pk(F0, z1, cmul_pk(G0, z0));
            const float2 nx1 = cfma_pk(G1, z3, cmul_pk(E1, z2));
            const float2 ny1 = cfma_pk(F1, z3, cmul_pk(G1, z2));
            z0 = nx0; z1 = ny0; z2 = nx1; z3 = ny1;
        };
        auto crossing = [&]() {
            const float2 pv3 = make_float2(dpp_up1(z3.x), dpp_up1(z3.y));
            const float2 nv0 = make_float2(dpp_dn1(z0.x), dpp_dn1(z0.y));
            const float2 t1 = cross_pk(CK, z1, z2);
            const float2 t2 = cross_pk(CK, z2, z1);
            z0 = cross_pk(EC0, z0, pv3);
            z3 = cross_pk(EC3, z3, nv0);
            z1 = t1; z2 = t2;
        };
        auto issue_chunk = [&](int c) {    // local chunk 0..7
            const float4* src = (const float4*)coefs + ((base + c) * 24) * 64 + lane;
            float4* dst = &cbuf[c & 1][0];
            #pragma unroll
            for (int q = 0; q < 24; ++q)
                __builtin_amdgcn_global_load_lds(
                    (const __attribute__((address_space(1))) void*)(src + q * 64),
                    (__attribute__((address_space(3))) void*)(dst + q * 64),
                    16, 0, 0);
        };

        issue_chunk(0);
        issue_chunk(1);
        asm volatile("s_waitcnt vmcnt(24)" ::: "memory");
        __builtin_amdgcn_sched_barrier(0);

        for (int c = 0; c < 7; ++c) {
            const int cb = c & 1;
            float4 KA[8], KB[8], KC[8];
            #pragma unroll
            for (int k = 0; k < 8; ++k) {
                const float4* p = &cbuf[cb][k * 192 + lane];
                KA[k] = p[0]; KB[k] = p[64]; KC[k] = p[128];
            }
            asm volatile("s_waitcnt lgkmcnt(0)" ::: "memory");
            __builtin_amdgcn_sched_barrier(0);
            if (c <= 5) issue_chunk(c + 2);
            #pragma unroll
            for (int k = 0; k < 8; ++k) {
                mstep(KA[k], KB[k], KC[k]);
                crossing();
            }
            if (c <= 5)
                asm volatile("s_waitcnt vmcnt(24)" ::: "memory");
            else
                asm volatile("s_waitcnt vmcnt(0)" ::: "memory");
            __builtin_amdgcn_sched_barrier(0);
        }
        {   // local chunk 7: g=0 -> s57..64 all crossing; g=1 -> s121..128
            float4 KA[8], KB[8], KC[8];
            #pragma unroll
            for (int k = 0; k < 8; ++k) {
                const float4* p = &cbuf[1][k * 192 + lane];
                KA[k] = p[0]; KB[k] = p[64]; KC[k] = p[128];
            }
            asm volatile("s_waitcnt lgkmcnt(0)" ::: "memory");
            __builtin_amdgcn_sched_barrier(0);
            #pragma unroll
            for (int k = 0; k < 7; ++k) {
                mstep(KA[k], KB[k], KC[k]);
                crossing();
            }
            mstep(KA[7], KB[7], KC[7]);
            if (g == 0) crossing();          // s=64 crossing; s=128 none
        }
        if (g == 1) {                        // fold D129 row phases
            float4 thF = *(const float4*)(thetas + 129 * N + 4 * lane);
            float sn[4], cs[4];
            sincos4(thF, sn, cs);
            z0 = cmul_pk(make_float2(cs[0], sn[0]), z0);
            z1 = cmul_pk(make_float2(cs[1], sn[1]), z1);
            z2 = cmul_pk(make_float2(cs[2], sn[2]), z2);
            z3 = cmul_pk(make_float2(cs[3], sn[3]), z3);
        }
        {   // store column col of P_g ROW-MAJOR float2
            float2* pb = (float2*)(ws + (g == 0 ? 98304 : 229376));
            const int r = 4 * lane;
            pb[(r + 0) * 256 + col] = z0;
            pb[(r + 1) * 256 + col] = z1;
            pb[(r + 2) * 256 + col] = z2;
            pb[(r + 3) * 256 + col] = z3;
        }
    }
    grid.sync();

    // ================= phase B: M = P2 x P1 (zero-LDS) =====================
    {
        const int r  = j >> 1;                    // output row
        const int c0 = (j & 1) * 128 + lane;      // cols c0, c0+64
        const float2* A = (const float2*)(ws + 229376) + (size_t)r * 256;
        const float2* B = (const float2*)(ws + 98304);

        float2 acc0 = make_float2(0.f, 0.f);
        float2 acc1 = make_float2(0.f, 0.f);
        #pragma unroll 8
        for (int k = 0; k < 256; ++k) {
            const float2 a  = A[k];                        // wave-uniform
            const float2 b0 = B[(size_t)k * 256 + c0];     // coalesced
            const float2 b1 = B[(size_t)k * 256 + c0 + 64];
            acc0 = cfma_pk(a, b0, acc0);
            acc1 = cfma_pk(a, b1, acc1);
        }
        const int i0 = r * 256 + c0;
        out[i0]              = acc0.x;
        out[65536 + i0]      = acc0.y;
        out[i0 + 64]         = acc1.x;
        out[65536 + i0 + 64] = acc1.y;
    }
}

extern "C" void kernel_launch(void* const* d_in, const int* in_sizes, int n_in,
                              void* d_out, int out_size, void* d_ws, size_t ws_size,
                              hipStream_t stream)
{
    const float* thetas = (const float*)d_in[0];   // [130,256] fp32
    float* out = (float*)d_out;                    // planar: re[65536] || im[65536]
    float* ws  = (float*)d_ws;
    (void)in_sizes; (void)n_in; (void)out_size; (void)ws_size;

    void* args[] = { (void*)&thetas, (void*)&ws, (void*)&out };
    hipLaunchCooperativeKernel((void*)fused_kernel, dim3(512), dim3(64),
                               args, 0, stream);
}

// Round 16
// 71.103 us; speedup vs baseline: 2.9189x; 2.9189x over previous
//
#include <hip/hip_runtime.h>

// NEUROPULS unitary mesh, N=256 — R19 = R16 verbatim (best: 71.8us).
// R18 post-mortem: cooperative grid.sync costs ~50-60us per sync on this
// runtime (fused kernel 143us) — decomposition direction definitively
// closed. R16 stands: coef kernel + monolithic 128-stage mesh with packed
// fp32 core, whole-chunk register hoist, counted-vmcnt DMA double-buffer.
// Dossier: per-stage ~226ns resisted instruction count (R6/R8/R16), memory
// source (R8/R9/R11), VGPR (R7), wave-parallel (R10), prefetch depth (R12),
// LDS-latency elimination (R15), packed math (R16), 3-launch split
// (R14/R17: launch gaps ~5-9us each eat the halving), cooperative fusion
// (R18: sync 10x a launch). Floor = 40us harness fill + ~3us coef + ~7us
// launch gap + ~29us mesh (128 x 226ns at idle DPM clock).

__device__ __forceinline__ float dpp_up1(float x) {   // wave_shr:1, n <- n-1
    return __int_as_float(__builtin_amdgcn_update_dpp(
        __float_as_int(x), __float_as_int(x), 0x138, 0xf, 0xf, false));
}
__device__ __forceinline__ float dpp_dn1(float x) {   // wave_shl:1, n <- n+1
    return __int_as_float(__builtin_amdgcn_update_dpp(
        __float_as_int(x), __float_as_int(x), 0x130, 0xf, 0xf, false));
}
__device__ __forceinline__ void sincos4(float4 th, float sn[4], float cs[4]) {
    __sincosf(th.x, &sn[0], &cs[0]);
    __sincosf(th.y, &sn[1], &cs[1]);
    __sincosf(th.z, &sn[2], &cs[2]);
    __sincosf(th.w, &sn[3], &cs[3]);
}

// t = K (x) z  (complex mul, z=[re,im], K=[Kr,Ki]) — 2 pk ops
__device__ __forceinline__ float2 cmul_pk(float2 K, float2 z) {
    float2 t;
    asm("v_pk_mul_f32 %0, %1, %2 op_sel:[0,0] op_sel_hi:[0,1]\n\t"
        "v_pk_fma_f32 %0, %1, %2, %0 op_sel:[1,1,0] op_sel_hi:[1,0,1] neg_lo:[1,0,0]"
        : "=&v"(t) : "v"(K), "v"(z));
    return t;
}
// acc += K (x) z — 2 pk ops
__device__ __forceinline__ float2 cfma_pk(float2 K, float2 z, float2 acc) {
    asm("v_pk_fma_f32 %0, %1, %2, %0 op_sel:[0,0,0] op_sel_hi:[0,1,1]\n\t"
        "v_pk_fma_f32 %0, %1, %2, %0 op_sel:[1,1,0] op_sel_hi:[1,0,1] neg_lo:[1,0,0]"
        : "+v"(acc) : "v"(K), "v"(z));
    return acc;
}
// t = [K.lo*z.re - K.hi*p.im, K.lo*z.im + K.hi*p.re]  (crossing row) — 2 pk
__device__ __forceinline__ float2 cross_pk(float2 K, float2 z, float2 p) {
    float2 t;
    asm("v_pk_mul_f32 %0, %1, %2 op_sel:[0,0] op_sel_hi:[0,1]\n\t"
        "v_pk_fma_f32 %0, %1, %3, %0 op_sel:[1,1,0] op_sel_hi:[1,0,1] neg_lo:[1,0,0]"
        : "=&v"(t) : "v"(K), "v"(z), "v"(p));
    return t;
}

// ---------- kernel 1: per-stage collapsed coefficients (verified) ----------
__global__ __launch_bounds__(64)
void coef_kernel(const float* __restrict__ thetas,  // [130,256]
                 float* __restrict__ coefs)         // 128*3*64 float4
{
    const int s0   = blockIdx.x;    // 0..127 -> theta row s0+1
    const int lane = threadIdx.x;   // 0..63

    const float U  = 0.98f * 0.505f;                  // AT^2
    const float W  = 0.98f * 0.495f;                  // AR^2
    const float Gc = 0.98f * sqrtf(0.505f * 0.495f);  // AT*AR

    float4 th = *(const float4*)(thetas + (s0 + 1) * 256 + 4 * lane);
    float s[4], c[4];
    sincos4(th, s, c);

    float4 A, B, C;
    A.x = U * c[0] - W * c[1];   A.y = U * s[0] - W * s[1];   // E0
    A.z = U * c[1] - W * c[0];   A.w = U * s[1] - W * s[0];   // F0
    B.x = -Gc * (s[0] + s[1]);   B.y = Gc * (c[0] + c[1]);    // G0
    B.z = -Gc * (s[2] + s[3]);   B.w = Gc * (c[2] + c[3]);    // G1
    C.x = U * c[2] - W * c[3];   C.y = U * s[2] - W * s[3];   // E1
    C.z = U * c[3] - W * c[2];   C.w = U * s[3] - W * s[2];   // F1

    float4* cp = (float4*)coefs;
    cp[(s0 * 3 + 0) * 64 + lane] = A;
    cp[(s0 * 3 + 1) * 64 + lane] = B;
    cp[(s0 * 3 + 2) * 64 + lane] = C;
}

// ---------- kernel 2: mesh state chain (packed core) ----------
__global__ __launch_bounds__(64, 1)
void neuropuls_mesh_kernel(const float* __restrict__ thetas,  // [130,256]
                           const float* __restrict__ coefs,   // ws (from k1)
                           float* __restrict__ out)           // re[65536] || im[65536]
{
    constexpr int N = 256;
    __shared__ float4 cbuf[2][1536];   // 2 x 24 KB (8-stage chunks)

    const int lane = threadIdx.x;   // 0..63
    const int col  = blockIdx.x;    // 0..255

    const float BT = sqrtf(0.98f * 0.01f);   // CR a*sqrt(CT)
    const float BR = sqrtf(0.98f * 0.99f);   // CR thru amplitude
    const float2 CK  = make_float2(BT, BR);
    const float2 EC0 = (lane == 0)  ? make_float2(BR, 0.f) : CK;  // row 0 thru
    const float2 EC3 = (lane == 63) ? make_float2(BR, 0.f) : CK;  // row 255 thru

    // state: rows 4*lane..4*lane+3 of the current column, packed [re,im]
    float2 z0 = make_float2(0.f, 0.f), z1 = z0, z2 = z0, z3 = z0;

    // arch0 = diag(exp(i*theta[0]))
    {
        const float th0 = thetas[col];
        float s0, c0;
        __sincosf(th0, &s0, &c0);
        const int r0 = col - 4 * lane;
        if (r0 == 0) z0 = make_float2(c0, s0);
        else if (r0 == 1) z1 = make_float2(c0, s0);
        else if (r0 == 2) z2 = make_float2(c0, s0);
        else if (r0 == 3) z3 = make_float2(c0, s0);
    }

    // mstep: x'=E(x)x + G(x)y ; y'=G(x)x + F(x)y per pair — 16 pk ops
    auto mstep = [&](const float4& KA, const float4& KB, const float4& KC) {
        const float2 E0 = make_float2(KA.x, KA.y), F0 = make_float2(KA.z, KA.w);
        const float2 G0 = make_float2(KB.x, KB.y), G1 = make_float2(KB.z, KB.w);
        const float2 E1 = make_float2(KC.x, KC.y), F1 = make_float2(KC.z, KC.w);
        const float2 nx0 = cfma_pk(G0, z1, cmul_pk(E0, z0));
        const float2 ny0 = cfma_pk(F0, z1, cmul_pk(G0, z0));
        const float2 nx1 = cfma_pk(G1, z3, cmul_pk(E1, z2));
        const float2 ny1 = cfma_pk(F1, z3, cmul_pk(G1, z2));
        z0 = nx0; z1 = ny0; z2 = nx1; z3 = ny1;
    };
    // crossing — 8 pk + 4 DPP
    auto crossing = [&]() {
        const float2 pv3 = make_float2(dpp_up1(z3.x), dpp_up1(z3.y));
        const float2 nv0 = make_float2(dpp_dn1(z0.x), dpp_dn1(z0.y));
        const float2 t1 = cross_pk(CK, z1, z2);
        const float2 t2 = cross_pk(CK, z2, z1);
        z0 = cross_pk(EC0, z0, pv3);
        z3 = cross_pk(EC3, z3, nv0);
        z1 = t1; z2 = t2;
    };

    // issue chunk c's 24 DMA segments (1 KB each) into cbuf[c&1]
    auto issue_chunk = [&](int c) {
        const float4* src = (const float4*)coefs + (c * 24) * 64 + lane;
        float4* dst = &cbuf[c & 1][0];
        #pragma unroll
        for (int j = 0; j < 24; ++j)
            __builtin_amdgcn_global_load_lds(
                (const __attribute__((address_space(1))) void*)(src + j * 64),
                (__attribute__((address_space(3))) void*)(dst + j * 64),
                16, 0, 0);
    };

    // ---- prologue: chunks 0,1 in flight; chunk 0 landed after vmcnt(24) ----
    issue_chunk(0);
    issue_chunk(1);
    asm volatile("s_waitcnt vmcnt(24)" ::: "memory");
    __builtin_amdgcn_sched_barrier(0);

    // chunks 0..14 (stages s = 8c+1 .. 8c+8, all with crossing: s <= 120)
    for (int c = 0; c < 15; ++c) {
        const int cb = c & 1;
        // hoist the whole chunk's coefs into registers (static indices)
        float4 KA[8], KB[8], KC[8];
        #pragma unroll
        for (int k = 0; k < 8; ++k) {
            const float4* p = &cbuf[cb][k * 192 + lane];
            KA[k] = p[0]; KB[k] = p[64]; KC[k] = p[128];
        }
        asm volatile("s_waitcnt lgkmcnt(0)" ::: "memory");   // reads done;
        __builtin_amdgcn_sched_barrier(0);                   // cbuf[cb] free
        if (c <= 13) issue_chunk(c + 2);                     // refill cbuf[cb]
        // ---- 8 stages of pure-register packed compute ----
        #pragma unroll
        for (int k = 0; k < 8; ++k) {
            mstep(KA[k], KB[k], KC[k]);
            crossing();
        }
        // gate: chunk c+1 fully landed before next iteration reads it
        if (c <= 13)
            asm volatile("s_waitcnt vmcnt(24)" ::: "memory");
        else
            asm volatile("s_waitcnt vmcnt(0)" ::: "memory"); // chunk 15 landed
        __builtin_amdgcn_sched_barrier(0);
    }

    // chunk 15 (buffer 1): stages s = 121..128; s=128 has no crossing
    {
        float4 KA[8], KB[8], KC[8];
        #pragma unroll
        for (int k = 0; k < 8; ++k) {
            const float4* p = &cbuf[1][k * 192 + lane];
            KA[k] = p[0]; KB[k] = p[64]; KC[k] = p[128];
        }
        asm volatile("s_waitcnt lgkmcnt(0)" ::: "memory");
        __builtin_amdgcn_sched_barrier(0);
        #pragma unroll
        for (int k = 0; k < 7; ++k) {      // s = 121..127
            mstep(KA[k], KB[k], KC[k]);
            crossing();
        }
        mstep(KA[7], KB[7], KC[7]);        // s = 128: mstep only
    }

    // final phase layer theta[129]: z *= exp(i*th) — complex mul
    {
        float4 thF = *(const float4*)(thetas + 129 * N + 4 * lane);
        float sn[4], cs[4];
        sincos4(thF, sn, cs);
        z0 = cmul_pk(make_float2(cs[0], sn[0]), z0);
        z1 = cmul_pk(make_float2(cs[1], sn[1]), z1);
        z2 = cmul_pk(make_float2(cs[2], sn[2]), z2);
        z3 = cmul_pk(make_float2(cs[3], sn[3]), z3);
    }

    // store PLANAR: real block then imag block, row-major [row][col]
    {
        const int r = 4 * lane;
        out[(r + 0) * N + col] = z0.x;  out[N * N + (r + 0) * N + col] = z0.y;
        out[(r + 1) * N + col] = z1.x;  out[N * N + (r + 1) * N + col] = z1.y;
        out[(r + 2) * N + col] = z2.x;  out[N * N + (r + 2) * N + col] = z2.y;
        out[(r + 3) * N + col] = z3.x;  out[N * N + (r + 3) * N + col] = z3.y;
    }
}

extern "C" void kernel_launch(void* const* d_in, const int* in_sizes, int n_in,
                              void* d_out, int out_size, void* d_ws, size_t ws_size,
                              hipStream_t stream)
{
    const float* thetas = (const float*)d_in[0];   // [130,256] fp32
    float* out   = (float*)d_out;                  // planar: re[65536] || im[65536]
    float* coefs = (float*)d_ws;                   // 128*3*64 float4 = 384 KB
    (void)in_sizes; (void)n_in; (void)out_size; (void)ws_size;

    coef_kernel<<<dim3(128), dim3(64), 0, stream>>>(thetas, coefs);
    neuropuls_mesh_kernel<<<dim3(256), dim3(64), 0, stream>>>(thetas, coefs, out);
}